// Round 1
// baseline (184.143 us; speedup 1.0000x reference)
//
#include <hip/hip_runtime.h>

// pyramid_roi_align (Mask R-CNN), MI355X.
// N=1000 boxes, C=256 channels, POOL=7, levels p2(256^2) p3(128^2) p4(64^2) p5(32^2), fp32.
// One block per box; 14 threads precompute shared interp tables; 256 threads
// then write the 256*49 output elements (49 iters each, coalesced stores).

#define POOL 7
#define NCH  256
#define ELEMS_PER_BOX (NCH * POOL * POOL)   // 12544 = 49 * 256

__global__ __launch_bounds__(256) void roi_align_kernel(
    const float* __restrict__ boxes,
    const float* __restrict__ p2, const float* __restrict__ p3,
    const float* __restrict__ p4, const float* __restrict__ p5,
    float* __restrict__ out, int N)
{
    const int n = blockIdx.x;
    if (n >= N) return;

    __shared__ int   s_y0[POOL], s_y1[POOL], s_x0[POOL], s_x1[POOL];
    __shared__ float s_ly[POOL], s_lx[POOL], s_vy[POOL], s_vx[POOL];
    __shared__ int   s_H;
    __shared__ const float* s_fmap;

    const int tid = threadIdx.x;

    if (tid < 2 * POOL) {
        // each of the 14 setup threads redundantly computes the level (cheap)
        const float by1 = boxes[4 * n + 0];
        const float bx1 = boxes[4 * n + 1];
        const float by2 = boxes[4 * n + 2];
        const float bx2 = boxes[4 * n + 3];
        const float h = by2 - by1;
        const float w = bx2 - bx1;
        // roi_level = clip(round(4 + log2(sqrt(h*w) / (224/1024))), 2, 5)
        // rintf = round-half-to-even, matching jnp.round
        float rl = 4.0f + log2f(sqrtf(h * w) / 0.21875f);
        int level = (int)rintf(rl);
        level = min(5, max(2, level));
        const int H = 256 >> (level - 2);
        if (tid == 0) {
            s_H = H;
            s_fmap = (level == 2) ? p2 : (level == 3) ? p3 : (level == 4) ? p4 : p5;
        }
        const bool isx = (tid >= POOL);
        const int  g   = isx ? tid - POOL : tid;
        const float c1 = isx ? bx1 : by1;
        const float c2 = isx ? bx2 : by2;
        // ys = (y1 + g/(POOL-1) * (y2-y1)) * (H-1), TF crop_and_resize semantics
        const float t  = (float)g / (float)(POOL - 1);
        const float s  = (c1 + t * (c2 - c1)) * (float)(H - 1);
        const float f0 = floorf(s);
        const float l  = s - f0;
        int i0 = (int)f0;
        i0 = min(H - 1, max(0, i0));
        const int i1 = min(H - 1, i0 + 1);
        const float v = (s >= 0.0f && s <= (float)(H - 1)) ? 1.0f : 0.0f;
        if (isx) { s_x0[g] = i0; s_x1[g] = i1; s_lx[g] = l; s_vx[g] = v; }
        else     { s_y0[g] = i0; s_y1[g] = i1; s_ly[g] = l; s_vy[g] = v; }
    }
    __syncthreads();

    const float* __restrict__ fmap = s_fmap;
    const int H = s_H;
    const int W = H;
    float* __restrict__ obase = out + (size_t)n * ELEMS_PER_BOX;

    // 12544 = 49 * 256 exactly -> every thread runs exactly 49 iterations
    for (int i = tid; i < ELEMS_PER_BOX; i += 256) {
        const int c  = i / 49;
        const int pp = i - c * 49;
        const int py = pp / 7;
        const int px = pp - py * 7;

        const float* __restrict__ f = fmap + (size_t)c * (H * W);
        const int y0 = s_y0[py], y1 = s_y1[py];
        const int x0 = s_x0[px], x1 = s_x1[px];

        const float v00 = f[y0 * W + x0];
        const float v10 = f[y1 * W + x0];
        const float v01 = f[y0 * W + x1];
        const float v11 = f[y1 * W + x1];

        const float ly = s_ly[py], lx = s_lx[px];
        const float wy0 = 1.0f - ly, wy1 = ly;
        const float wx0 = 1.0f - lx, wx1 = lx;

        float val = (v00 * wy0 + v10 * wy1) * wx0 + (v01 * wy0 + v11 * wy1) * wx1;
        val *= s_vy[py] * s_vx[px];

        obase[i] = val;
    }
}

extern "C" void kernel_launch(void* const* d_in, const int* in_sizes, int n_in,
                              void* d_out, int out_size, void* d_ws, size_t ws_size,
                              hipStream_t stream) {
    const float* boxes = (const float*)d_in[0];
    const float* p2    = (const float*)d_in[1];
    const float* p3    = (const float*)d_in[2];
    const float* p4    = (const float*)d_in[3];
    const float* p5    = (const float*)d_in[4];
    float* out = (float*)d_out;
    const int N = in_sizes[0] / 4;

    roi_align_kernel<<<N, 256, 0, stream>>>(boxes, p2, p3, p4, p5, out, N);
}

// Round 2
// 154.086 us; speedup vs baseline: 1.1951x; 1.1951x over previous
//
#include <hip/hip_runtime.h>

// pyramid_roi_align (Mask R-CNN), MI355X.
// N=1000 boxes, C=256 channels, POOL=7, levels p2(256^2) p3(128^2) p4(64^2) p5(32^2), fp32.
//
// R2: latency-bound fix. Grid = N*7 blocks (each block does 1/7 of a box's
// 12544 output elements); every thread handles exactly 7 elements, fully
// unrolled so all 28 gathers are in flight before the first use. Box id =
// bid % N so a box's 7 chunks are 1000 apart (1000 % 8 == 0 -> same XCD
// under round-robin dispatch, sharing the tap window in one L2).

#define POOL 7
#define NCH  256
#define ELEMS_PER_BOX (NCH * POOL * POOL)   // 12544 = 49 * 256
#define CHUNKS 7
#define CHUNK_ELEMS (ELEMS_PER_BOX / CHUNKS) // 1792 = 7 * 256

__global__ __launch_bounds__(256) void roi_align_kernel(
    const float* __restrict__ boxes,
    const float* __restrict__ p2, const float* __restrict__ p3,
    const float* __restrict__ p4, const float* __restrict__ p5,
    float* __restrict__ out, int N)
{
    const int bid   = blockIdx.x;
    const int n     = bid % N;         // box index (chunks of a box 1000 apart)
    const int chunk = bid / N;         // 0..6

    __shared__ int   s_y0[POOL], s_y1[POOL], s_x0[POOL], s_x1[POOL];
    __shared__ float s_ly[POOL], s_lx[POOL], s_vy[POOL], s_vx[POOL];
    __shared__ int   s_H;
    __shared__ const float* s_fmap;

    const int tid = threadIdx.x;

    if (tid < 2 * POOL) {
        const float by1 = boxes[4 * n + 0];
        const float bx1 = boxes[4 * n + 1];
        const float by2 = boxes[4 * n + 2];
        const float bx2 = boxes[4 * n + 3];
        const float h = by2 - by1;
        const float w = bx2 - bx1;
        // roi_level = clip(round(4 + log2(sqrt(h*w) / (224/1024))), 2, 5)
        float rl = 4.0f + log2f(sqrtf(h * w) / 0.21875f);
        int level = (int)rintf(rl);             // round-half-even = jnp.round
        level = min(5, max(2, level));
        const int H = 256 >> (level - 2);
        if (tid == 0) {
            s_H = H;
            s_fmap = (level == 2) ? p2 : (level == 3) ? p3 : (level == 4) ? p4 : p5;
        }
        const bool isx = (tid >= POOL);
        const int  g   = isx ? tid - POOL : tid;
        const float c1 = isx ? bx1 : by1;
        const float c2 = isx ? bx2 : by2;
        const float t  = (float)g / (float)(POOL - 1);
        const float s  = (c1 + t * (c2 - c1)) * (float)(H - 1);
        const float f0 = floorf(s);
        const float l  = s - f0;
        int i0 = (int)f0;
        i0 = min(H - 1, max(0, i0));
        const int i1 = min(H - 1, i0 + 1);
        const float v = (s >= 0.0f && s <= (float)(H - 1)) ? 1.0f : 0.0f;
        if (isx) { s_x0[g] = i0; s_x1[g] = i1; s_lx[g] = l; s_vx[g] = v; }
        else     { s_y0[g] = i0; s_y1[g] = i1; s_ly[g] = l; s_vy[g] = v; }
    }
    __syncthreads();

    const float* __restrict__ fmap = s_fmap;
    const int H = s_H;
    const int W = H;
    float* __restrict__ obase = out + (size_t)n * ELEMS_PER_BOX + chunk * CHUNK_ELEMS;
    const int ibase = chunk * CHUNK_ELEMS + tid;

    // Phase 1: compute all addresses + weights, issue all 28 loads.
    float v00[CHUNKS], v10[CHUNKS], v01[CHUNKS], v11[CHUNKS];
    float wgt[CHUNKS][4];
    float vv[CHUNKS];

#pragma unroll
    for (int k = 0; k < CHUNKS; ++k) {
        const int i  = ibase + k * 256;
        const int c  = i / 49;
        const int pp = i - c * 49;
        const int py = pp / 7;
        const int px = pp - py * 7;

        const float* __restrict__ f = fmap + (size_t)c * (H * W);
        const int y0 = s_y0[py], y1 = s_y1[py];
        const int x0 = s_x0[px], x1 = s_x1[px];

        v00[k] = f[y0 * W + x0];
        v10[k] = f[y1 * W + x0];
        v01[k] = f[y0 * W + x1];
        v11[k] = f[y1 * W + x1];

        const float ly = s_ly[py], lx = s_lx[px];
        wgt[k][0] = (1.0f - ly) * (1.0f - lx);
        wgt[k][1] = ly * (1.0f - lx);
        wgt[k][2] = (1.0f - ly) * lx;
        wgt[k][3] = ly * lx;
        vv[k] = s_vy[py] * s_vx[px];
    }

    // Phase 2: combine and store (coalesced, 1 KB/wave).
#pragma unroll
    for (int k = 0; k < CHUNKS; ++k) {
        float val = v00[k] * wgt[k][0] + v10[k] * wgt[k][1]
                  + v01[k] * wgt[k][2] + v11[k] * wgt[k][3];
        obase[tid + k * 256] = val * vv[k];
    }
}

extern "C" void kernel_launch(void* const* d_in, const int* in_sizes, int n_in,
                              void* d_out, int out_size, void* d_ws, size_t ws_size,
                              hipStream_t stream) {
    const float* boxes = (const float*)d_in[0];
    const float* p2    = (const float*)d_in[1];
    const float* p3    = (const float*)d_in[2];
    const float* p4    = (const float*)d_in[3];
    const float* p5    = (const float*)d_in[4];
    float* out = (float*)d_out;
    const int N = in_sizes[0] / 4;

    roi_align_kernel<<<N * CHUNKS, 256, 0, stream>>>(boxes, p2, p3, p4, p5, out, N);
}

// Round 3
// 142.770 us; speedup vs baseline: 1.2898x; 1.0793x over previous
//
#include <hip/hip_runtime.h>

// pyramid_roi_align (Mask R-CNN), MI355X.
// R3: halve the gather stream. x-taps are adjacent columns -> one float2 load
// per (row,cell) instead of two dwords (28 -> 14 gathers/thread). Per-cell
// interp params (row offsets + folded weights) precomputed into a 49-entry
// LDS table; hot loop uses incremental c/pp updates (no div/mod) and issues
// all 14 float2 loads before any use.

#define POOL 7
#define NCH  256
#define ELEMS_PER_BOX (NCH * POOL * POOL)    // 12544 = 49 * 256
#define CHUNKS 7
#define CHUNK_ELEMS (ELEMS_PER_BOX / CHUNKS) // 1792

typedef float f2 __attribute__((ext_vector_type(2)));

__global__ __launch_bounds__(256) void roi_align_kernel(
    const float* __restrict__ boxes,
    const float* __restrict__ p2, const float* __restrict__ p3,
    const float* __restrict__ p4, const float* __restrict__ p5,
    float* __restrict__ out, int N)
{
    const int bid   = blockIdx.x;
    const int n     = bid % N;     // chunks of one box are 1000 apart -> same XCD
    const int chunk = bid / N;

    // per-cell tables (49 cells)
    __shared__ int   s_off0[49], s_off1[49];          // y0*W+xb, y1*W+xb
    __shared__ float s_a[49], s_b[49];                // x-weights (vx folded)
    __shared__ float s_w0[49], s_w1[49];              // y-weights (vy folded)
    __shared__ int   s_HW;
    __shared__ const float* s_fmap;

    const int tid = threadIdx.x;

    if (tid < 49) {
        const float by1 = boxes[4 * n + 0];
        const float bx1 = boxes[4 * n + 1];
        const float by2 = boxes[4 * n + 2];
        const float bx2 = boxes[4 * n + 3];
        const float h = by2 - by1;
        const float w = bx2 - bx1;
        float rl = 4.0f + log2f(sqrtf(h * w) / 0.21875f);
        int level = (int)rintf(rl);            // round-half-even = jnp.round
        level = min(5, max(2, level));
        const int H = 256 >> (level - 2);
        const int W = H;
        if (tid == 0) {
            s_HW = H * W;
            s_fmap = (level == 2) ? p2 : (level == 3) ? p3 : (level == 4) ? p4 : p5;
        }
        const int py = tid / 7;
        const int px = tid - 7 * py;

        // y interp
        const float ty = (float)py / (float)(POOL - 1);
        const float ys = (by1 + ty * (by2 - by1)) * (float)(H - 1);
        const float yf = floorf(ys);
        const float ly = ys - yf;
        int y0 = (int)yf; y0 = min(H - 1, max(0, y0));
        const int y1 = min(H - 1, y0 + 1);
        const float vy = (ys >= 0.0f && ys <= (float)(H - 1)) ? 1.0f : 0.0f;

        // x interp
        const float tx = (float)px / (float)(POOL - 1);
        const float xs = (bx1 + tx * (bx2 - bx1)) * (float)(W - 1);
        const float xf = floorf(xs);
        const float lx = xs - xf;
        int x0 = (int)xf; x0 = min(W - 1, max(0, x0));
        const float vx = (xs >= 0.0f && xs <= (float)(W - 1)) ? 1.0f : 0.0f;

        const int xb = min(x0, W - 2);         // float2 base column
        // normal: q.x=col x0, q.y=col x0+1 -> a=wx0, b=wx1
        // edge (x0==W-1==xb+1): q.y=col W-1=x0=x1 -> a=0, b=wx0+wx1=1
        const bool edge = (x0 != xb);
        const float a = edge ? 0.0f : vx * (1.0f - lx);
        const float b = edge ? vx : vx * lx;

        s_off0[tid] = y0 * W + xb;
        s_off1[tid] = y1 * W + xb;
        s_a[tid] = a;
        s_b[tid] = b;
        s_w0[tid] = vy * (1.0f - ly);
        s_w1[tid] = vy * ly;
    }
    __syncthreads();

    const float* __restrict__ fmap = s_fmap;
    const int HW = s_HW;

    // starting flat index for this thread
    const int i0 = chunk * CHUNK_ELEMS + tid;
    int c  = i0 / 49;
    int pp = i0 - c * 49;

    // Phase 1: issue all 14 float2 gathers
    f2  q0[CHUNKS], q1[CHUNKS];
    int cell[CHUNKS];
    {
        int cc = c, p = pp;
#pragma unroll
        for (int k = 0; k < CHUNKS; ++k) {
            cell[k] = p;
            const float* plane = fmap + (size_t)cc * HW;
            q0[k] = *(const f2*)(plane + s_off0[p]);
            q1[k] = *(const f2*)(plane + s_off1[p]);
            // advance by 256 elements: 256 = 5*49 + 11
            cc += 5; p += 11;
            if (p >= 49) { p -= 49; cc += 1; }
        }
    }

    // Phase 2: combine + coalesced store
    float* __restrict__ obase = out + (size_t)n * ELEMS_PER_BOX + chunk * CHUNK_ELEMS;
#pragma unroll
    for (int k = 0; k < CHUNKS; ++k) {
        const int p = cell[k];
        const float a = s_a[p], b = s_b[p];
        const float r0 = q0[k].x * a + q0[k].y * b;
        const float r1 = q1[k].x * a + q1[k].y * b;
        obase[tid + k * 256] = r0 * s_w0[p] + r1 * s_w1[p];
    }
}

extern "C" void kernel_launch(void* const* d_in, const int* in_sizes, int n_in,
                              void* d_out, int out_size, void* d_ws, size_t ws_size,
                              hipStream_t stream) {
    const float* boxes = (const float*)d_in[0];
    const float* p2    = (const float*)d_in[1];
    const float* p3    = (const float*)d_in[2];
    const float* p4    = (const float*)d_in[3];
    const float* p5    = (const float*)d_in[4];
    float* out = (float*)d_out;
    const int N = in_sizes[0] / 4;

    roi_align_kernel<<<N * CHUNKS, 256, 0, stream>>>(boxes, p2, p3, p4, p5, out, N);
}